// Round 3
// baseline (489.965 us; speedup 1.0000x reference)
//
#include <hip/hip_runtime.h>
#include <math.h>

#define Vv   50000
#define EMB  128
#define Hh   256
#define TKk  400
#define Bb   128
#define OOVn 10
#define N2n  512
#define VOo  50010   // V + OOV
#define GNBLK 391    // ceil(50000 / 128)
#define PSTR 400     // partial stride (>= GNBLK)

typedef __bf16 bf16x8 __attribute__((ext_vector_type(8)));
typedef float  f32x4  __attribute__((ext_vector_type(4)));

__device__ __forceinline__ float sigf(float x) { return 1.f / (1.f + __expf(-x)); }
__device__ __forceinline__ float tanh_fast(float x) {
    x = fminf(15.f, fmaxf(-15.f, x));
    float e = __expf(2.f * x);
    return (e - 1.f) / (e + 1.f);
}
__device__ __forceinline__ float wave_red(float v) {
    #pragma unroll
    for (int o = 32; o; o >>= 1) v += __shfl_down(v, o);
    return v;
}
__device__ __forceinline__ float wave_max(float v) {
    #pragma unroll
    for (int o = 32; o; o >>= 1) v = fmaxf(v, __shfl_down(v, o));
    return v;
}
// fp32 -> bf16 RNE
__device__ __forceinline__ unsigned short f2bf(float f) {
    unsigned u = __builtin_bit_cast(unsigned, f);
    unsigned r = u + 0x7fffu + ((u >> 16) & 1u);
    return (unsigned short)(r >> 16);
}

// ---------------------------------------------------------------------------
// K1 "k_pre": the ENTIRE per-b pipeline in one block per b.
//   x -> LSTM -> dec_fea -> scores -> softmax/coverage -> ctx -> out(abf)
//   -> p_gen.  1024 threads = 16 waves. All intermediates in LDS.
// ---------------------------------------------------------------------------
__global__ __launch_bounds__(1024) void k_pre(
    const int* __restrict__ y, const float* __restrict__ ct1,
    const float* __restrict__ emb, const float* __restrict__ Wx,
    const float* __restrict__ bx,
    const float* __restrict__ h0, const float* __restrict__ c0,
    const float* __restrict__ wih, const float* __restrict__ bih,
    const float* __restrict__ whh, const float* __restrict__ bhh,
    const float* __restrict__ Wp, const float* __restrict__ bp,
    const float* __restrict__ ef, const float* __restrict__ covi,
    const float* __restrict__ Wc, const float* __restrict__ vw,
    const float* __restrict__ mask, const float* __restrict__ eo,
    const float* __restrict__ W1, const float* __restrict__ b1,
    const float* __restrict__ Wpg, const float* __restrict__ bpg,
    float* __restrict__ h1o, float* __restrict__ c1o,
    float* __restrict__ cto, float* __restrict__ attno,
    float* __restrict__ covo, float* __restrict__ pgo,
    unsigned short* __restrict__ abf)
{
    const int b = blockIdx.x;
    const int tid = threadIdx.x;
    const int wv = tid >> 6, l = tid & 63;

    __shared__ float ld_in[640];          // [ct1(512) | emb(128)]
    __shared__ float h0s[256], c0s[256];
    __shared__ float xws[128];
    __shared__ float gs[1024];            // gate sums; reused as ctx partials
    __shared__ float h1s[256], c1s[256];
    __shared__ float dfs[512];
    __shared__ float scs[400];
    __shared__ float as_[400];
    __shared__ float cts[512];
    __shared__ float red[16];
    __shared__ float bc2;

    // ---- P0: load per-b inputs ----
    if (tid < 512) ld_in[tid] = ct1[b * 512 + tid];
    if (tid < 128) ld_in[512 + tid] = emb[(size_t)y[b] * 128 + tid];
    if (tid >= 512 && tid < 768) { int n = tid - 512; h0s[n] = h0[b * 256 + n]; }
    if (tid >= 768)              { int n = tid - 768; c0s[n] = c0[b * 256 + n]; }
    __syncthreads();

    // ---- P1: x[j] = ld_in . Wx[j,:] + bx[j],  j=0..127 ----
    #pragma unroll
    for (int jj = 0; jj < 8; jj++) {
        int j = wv + jj * 16;
        float a = 0.f;
        #pragma unroll
        for (int i = 0; i < 10; i++) a += ld_in[l + 64 * i] * Wx[(size_t)j * 640 + l + 64 * i];
        a = wave_red(a);
        if (l == 0) xws[j] = a + bx[j];
    }
    __syncthreads();

    // ---- P2: gates + LSTM ----
    for (int jj = 0; jj < 64; jj++) {
        int j = wv + jj * 16;
        float a = xws[l] * wih[(size_t)j * 128 + l]
                + xws[l + 64] * wih[(size_t)j * 128 + l + 64];
        #pragma unroll
        for (int i = 0; i < 4; i++) a += h0s[l + 64 * i] * whh[(size_t)j * 256 + l + 64 * i];
        a = wave_red(a);
        if (l == 0) gs[j] = a + bih[j] + bhh[j];
    }
    __syncthreads();
    if (tid < 256) {
        int n = tid;
        float ig = sigf(gs[n]);
        float fg = sigf(gs[256 + n]);
        float gg = tanh_fast(gs[512 + n]);
        float og = sigf(gs[768 + n]);
        float c1v = fg * c0s[n] + ig * gg;
        float h1v = og * tanh_fast(c1v);
        h1s[n] = h1v; c1s[n] = c1v;
        h1o[b * 256 + n] = h1v; c1o[b * 256 + n] = c1v;
    }
    __syncthreads();

    // ---- P3: dec_fea[j] = [h1,c1] . Wp[j,:] + bp[j],  j=0..511 ----
    for (int jj = 0; jj < 32; jj++) {
        int j = wv + jj * 16;
        float a = 0.f;
        #pragma unroll
        for (int i = 0; i < 4; i++) a += h1s[l + 64 * i] * Wp[(size_t)j * 512 + l + 64 * i];
        #pragma unroll
        for (int i = 0; i < 4; i++) a += c1s[l + 64 * i] * Wp[(size_t)j * 512 + 256 + l + 64 * i];
        a = wave_red(a);
        if (l == 0) dfs[j] = a + bp[j];
    }
    __syncthreads();

    // ---- P4: scores[t], t=0..399 ----
    {
        float4 wc4[2], vv4[2];
        #pragma unroll
        for (int i = 0; i < 2; i++) {
            int n0 = l * 4 + i * 256;
            wc4[i] = *(const float4*)(Wc + n0);
            vv4[i] = *(const float4*)(vw + n0);
        }
        for (int tt = 0; tt < 25; tt++) {
            int t = wv + tt * 16;
            float cv = covi[b * 400 + t];
            float acc = 0.f;
            #pragma unroll
            for (int i = 0; i < 2; i++) {
                int n0 = l * 4 + i * 256;
                float4 ev = *(const float4*)(ef + ((size_t)(b * 400 + t)) * 512 + n0);
                float4 dv = *(const float4*)(&dfs[n0]);
                acc += tanh_fast(ev.x + dv.x + cv * wc4[i].x) * vv4[i].x;
                acc += tanh_fast(ev.y + dv.y + cv * wc4[i].y) * vv4[i].y;
                acc += tanh_fast(ev.z + dv.z + cv * wc4[i].z) * vv4[i].z;
                acc += tanh_fast(ev.w + dv.w + cv * wc4[i].w) * vv4[i].w;
            }
            acc = wave_red(acc);
            if (l == 0) scs[t] = acc;
        }
    }
    __syncthreads();

    // ---- P5: masked softmax + coverage ----
    {
        float s = (tid < 400) ? scs[tid] : -3.4e38f;
        float m = wave_max(s);
        if (l == 0) red[wv] = m;
        __syncthreads();
        if (tid == 0) {
            float t = red[0];
            for (int i = 1; i < 16; i++) t = fmaxf(t, red[i]);
            bc2 = t;
        }
        __syncthreads();
        float M = bc2;
        float w = (tid < 400) ? __expf(s - M) * mask[b * 400 + tid] : 0.f;
        float ss = wave_red(w);
        if (l == 0) red[wv] = ss;
        __syncthreads();
        if (tid == 0) {
            float t = 0.f;
            for (int i = 0; i < 16; i++) t += red[i];
            bc2 = t;
        }
        __syncthreads();
        float a = w / bc2;
        if (tid < 400) {
            as_[tid] = a;
            attno[b * 400 + tid] = a;
            covo[b * 400 + tid] = covi[b * 400 + tid] + a;
        }
    }
    __syncthreads();

    // ---- P6: ctx  c_t[n] = sum_t attn[t]*eo[b,t,n] ----
    {
        int n = tid & 511, half = tid >> 9;
        const float* p = eo + ((size_t)b * 400 + half * 200) * 512 + n;
        float acc = 0.f;
        #pragma unroll 4
        for (int t = 0; t < 200; t++) acc += as_[half * 200 + t] * p[(size_t)t * 512];
        gs[half * 512 + n] = acc;
    }
    __syncthreads();
    if (tid < 512) {
        float ctv = gs[tid] + gs[512 + tid];
        cts[tid] = ctv;
        cto[b * 512 + tid] = ctv;
    }
    __syncthreads();

    // ---- P7: out[j] = [h1,ct] . W1[j,:] + b1[j]  -> abf bf16 ----
    #pragma unroll
    for (int jj = 0; jj < 16; jj++) {
        int j = wv + jj * 16;
        float a = 0.f;
        #pragma unroll
        for (int i = 0; i < 4; i++) a += h1s[l + 64 * i] * W1[(size_t)j * 768 + l + 64 * i];
        #pragma unroll
        for (int i = 0; i < 8; i++) a += cts[l + 64 * i] * W1[(size_t)j * 768 + 256 + l + 64 * i];
        a = wave_red(a);
        if (l == 0) abf[b * 256 + j] = f2bf(a + b1[j]);
    }

    // ---- P8: p_gen = sigmoid([ct,h1,c1,x] . Wpg + bpg) ----
    {
        float pa;
        if (tid < 512)       pa = cts[tid] * Wpg[tid];
        else if (tid < 768)  pa = h1s[tid - 512] * Wpg[tid];
        else                 pa = c1s[tid - 768] * Wpg[tid];
        if (tid < 128) pa += xws[tid] * Wpg[1024 + tid];
        pa = wave_red(pa);
        __syncthreads();   // red[] reuse
        if (l == 0) red[wv] = pa;
        __syncthreads();
        if (tid == 0) {
            float t = 0.f;
            for (int i = 0; i < 16; i++) t += red[i];
            pgo[b] = sigf(t + bpg[0]);
        }
    }
}

// ---------------------------------------------------------------------------
// K2 "k_gemm": logits[128,50000] = A[128,256](bf16) @ W2^T + b2  (+ fused
// per-block softmax partials).  256 thr / 4 waves; 128 cols per block
// (wave w: cols w*32..w*32+31 as two 16-col n-tiles).  A staged ONCE in
// 64KB LDS with XOR-row swizzle (2-way residual bank aliasing = free);
// B read from W2 fp32 + inline cvt (no separate convert pass).
// Frag layouts as verified in prior rounds: A[m=ln][k=q*8+j],
// B[k=q*8+j][n=ln], D row=q*4+r col=ln.
// ---------------------------------------------------------------------------
__global__ __launch_bounds__(256, 2) void k_gemm(
    const unsigned short* __restrict__ abf, const float* __restrict__ W2,
    const float* __restrict__ b2, float* __restrict__ fd,
    float* __restrict__ pM, float* __restrict__ pS)
{
    __shared__ unsigned short As[128 * 256];   // 64KB, swizzled
    const int tid = threadIdx.x;
    const int w = tid >> 6, lane = tid & 63;
    const int ln = lane & 15, q = lane >> 4;

    // stage A: chunk c = (row, c8): global abf[row*256 + c8*8], 16B each
    #pragma unroll
    for (int i = 0; i < 16; i++) {
        int c = tid + i * 256;
        int row = c >> 5, c8 = c & 31;
        *(bf16x8*)(As + ((size_t)row * 32 + (c8 ^ (row & 7))) * 8) =
            *(const bf16x8*)(abf + (size_t)row * 256 + c8 * 8);
    }
    __syncthreads();

    const int vc0 = blockIdx.x * 128 + w * 32 + ln;
    const int vc1 = vc0 + 16;
    const bool va0 = vc0 < Vv, va1 = vc1 < Vv;
    const float* bp0 = W2 + (size_t)(va0 ? vc0 : 0) * 256 + q * 8;
    const float* bp1 = W2 + (size_t)(va1 ? vc1 : 0) * 256 + q * 8;

    f32x4 acc0[8] = {};
    f32x4 acc1[8] = {};

    #pragma unroll
    for (int kk8 = 0; kk8 < 32; kk8 += 4) {     // kk = kk8*8 elements
        int kk = kk8 * 8;
        float4 x0 = *(const float4*)(bp0 + kk);
        float4 x1 = *(const float4*)(bp0 + kk + 4);
        float4 y0 = *(const float4*)(bp1 + kk);
        float4 y1 = *(const float4*)(bp1 + kk + 4);
        unsigned short bu0[8] = { f2bf(x0.x), f2bf(x0.y), f2bf(x0.z), f2bf(x0.w),
                                  f2bf(x1.x), f2bf(x1.y), f2bf(x1.z), f2bf(x1.w) };
        unsigned short bu1[8] = { f2bf(y0.x), f2bf(y0.y), f2bf(y0.z), f2bf(y0.w),
                                  f2bf(y1.x), f2bf(y1.y), f2bf(y1.z), f2bf(y1.w) };
        bf16x8 bf0 = *(const bf16x8*)bu0;
        bf16x8 bf1 = *(const bf16x8*)bu1;
        int c8 = q + kk8;
        #pragma unroll
        for (int mt = 0; mt < 8; mt++) {
            int row = mt * 16 + ln;
            bf16x8 afr = *(const bf16x8*)(As + ((size_t)row * 32 + (c8 ^ (row & 7))) * 8);
            acc0[mt] = __builtin_amdgcn_mfma_f32_16x16x32_bf16(afr, bf0, acc0[mt], 0, 0, 0);
            acc1[mt] = __builtin_amdgcn_mfma_f32_16x16x32_bf16(afr, bf1, acc1[mt], 0, 0, 0);
        }
    }

    float bias0 = va0 ? b2[vc0] : 0.f;
    float bias1 = va1 ? b2[vc1] : 0.f;

    __syncthreads();                 // A-LDS reads done; reuse as scratch
    float* Mw   = (float*)As;        // [4][128]
    float* Sw   = Mw + 512;          // [4][128]
    float* Mrow = Sw + 512;          // [128]

    #pragma unroll
    for (int mt = 0; mt < 8; mt++) {
        #pragma unroll
        for (int r = 0; r < 4; r++) {
            int row = mt * 16 + q * 4 + r;
            float v0 = acc0[mt][r] + bias0;
            float v1 = acc1[mt][r] + bias1;
            if (va0) fd[(size_t)row * VOo + vc0] = v0;
            if (va1) fd[(size_t)row * VOo + vc1] = v1;
            float mx = fmaxf(va0 ? v0 : -3.4e38f, va1 ? v1 : -3.4e38f);
            mx = fmaxf(mx, __shfl_xor(mx, 1));
            mx = fmaxf(mx, __shfl_xor(mx, 2));
            mx = fmaxf(mx, __shfl_xor(mx, 4));
            mx = fmaxf(mx, __shfl_xor(mx, 8));
            if (ln == 0) Mw[w * 128 + row] = mx;
        }
    }
    __syncthreads();
    if (tid < 128)
        Mrow[tid] = fmaxf(fmaxf(Mw[tid], Mw[128 + tid]),
                          fmaxf(Mw[256 + tid], Mw[384 + tid]));
    __syncthreads();
    #pragma unroll
    for (int mt = 0; mt < 8; mt++) {
        #pragma unroll
        for (int r = 0; r < 4; r++) {
            int row = mt * 16 + q * 4 + r;
            float M = Mrow[row];
            float ev = (va0 ? __expf(acc0[mt][r] + bias0 - M) : 0.f)
                     + (va1 ? __expf(acc1[mt][r] + bias1 - M) : 0.f);
            ev += __shfl_xor(ev, 1);
            ev += __shfl_xor(ev, 2);
            ev += __shfl_xor(ev, 4);
            ev += __shfl_xor(ev, 8);
            if (ln == 0) Sw[w * 128 + row] = ev;
        }
    }
    __syncthreads();
    if (tid < 128) {
        pM[(size_t)tid * PSTR + blockIdx.x] = Mrow[tid];
        pS[(size_t)tid * PSTR + blockIdx.x] =
            Sw[tid] + Sw[128 + tid] + Sw[256 + tid] + Sw[384 + tid];
    }
}

// ---------------------------------------------------------------------------
// K3 "k_vs": combine partials + normalize + p_gen scale + OOV tail +
// pointer scatter-add.  One block per b owns the whole fd row, so
// normalize-then-scatter is ordered by __syncthreads (no cross-block race).
// ---------------------------------------------------------------------------
__global__ __launch_bounds__(1024) void k_vs(
    const float* __restrict__ pM, const float* __restrict__ pS,
    const float* __restrict__ pgen, const float* __restrict__ extra,
    const int* __restrict__ ebev, const float* __restrict__ attn,
    float* __restrict__ fd)
{
    const int b = blockIdx.x;
    const int tid = threadIdx.x;
    const int wv = tid >> 6, l = tid & 63;
    __shared__ float mredA[16], sredA[16];
    __shared__ float fMS[2];

    float m = -3.4e38f, s = 0.f;
    for (int i = tid; i < GNBLK; i += 1024) {
        float mi = pM[(size_t)b * PSTR + i];
        float si = pS[(size_t)b * PSTR + i];
        float M2 = fmaxf(m, mi);
        s = s * __expf(m - M2) + si * __expf(mi - M2);
        m = M2;
    }
    #pragma unroll
    for (int off = 32; off; off >>= 1) {
        float mo = __shfl_down(m, off);
        float so = __shfl_down(s, off);
        float M2 = fmaxf(m, mo);
        s = s * __expf(m - M2) + so * __expf(mo - M2);
        m = M2;
    }
    if (l == 0) { mredA[wv] = m; sredA[wv] = s; }
    __syncthreads();
    if (tid == 0) {
        float M = mredA[0], S = sredA[0];
        for (int i = 1; i < 16; i++) {
            float M2 = fmaxf(M, mredA[i]);
            S = S * __expf(M - M2) + sredA[i] * __expf(mredA[i] - M2);
            M = M2;
        }
        fMS[0] = M; fMS[1] = S;
    }
    __syncthreads();
    float M = fMS[0];
    float scale = pgen[b] / fMS[1];
    float* lrow = fd + (size_t)b * VOo;
    for (int v = tid; v < Vv; v += 1024) lrow[v] = __expf(lrow[v] - M) * scale;
    if (tid < OOVn) lrow[Vv + tid] = extra[b * OOVn + tid];
    __syncthreads();
    if (tid < TKk) {
        float w = (1.f - pgen[b]) * attn[b * TKk + tid];
        atomicAdd(lrow + ebev[b * TKk + tid], w);
    }
}

extern "C" void kernel_launch(void* const* d_in, const int* in_sizes, int n_in,
                              void* d_out, int out_size, void* d_ws, size_t ws_size,
                              hipStream_t stream)
{
    (void)in_sizes; (void)n_in; (void)out_size; (void)ws_size;

    const int*   y    = (const int*)d_in[0];
    const float* h0   = (const float*)d_in[1];
    const float* c0   = (const float*)d_in[2];
    const float* eo   = (const float*)d_in[3];
    const float* ef   = (const float*)d_in[4];
    const float* mask = (const float*)d_in[5];
    const float* ct1  = (const float*)d_in[6];
    const float* xz   = (const float*)d_in[7];
    const int*   ebev = (const int*)d_in[8];
    const float* cov  = (const float*)d_in[9];
    const float* emb  = (const float*)d_in[11];
    const float* Wx   = (const float*)d_in[12];
    const float* bx   = (const float*)d_in[13];
    const float* wih  = (const float*)d_in[14];
    const float* bih  = (const float*)d_in[15];
    const float* whh  = (const float*)d_in[16];
    const float* bhh  = (const float*)d_in[17];
    const float* Wp   = (const float*)d_in[18];
    const float* bp   = (const float*)d_in[19];
    const float* vw   = (const float*)d_in[20];
    const float* Wc   = (const float*)d_in[21];
    const float* Wpg  = (const float*)d_in[22];
    const float* bpg  = (const float*)d_in[23];
    const float* W1   = (const float*)d_in[24];
    const float* b1   = (const float*)d_in[25];
    const float* W2   = (const float*)d_in[26];
    const float* b2   = (const float*)d_in[27];

    float* out   = (float*)d_out;
    float* fd    = out;                              // [B, VO]
    float* h1o   = out + (size_t)Bb * VOo;           // [B, H]
    float* c1o   = h1o + (size_t)Bb * Hh;            // [B, H]
    float* cto   = c1o + (size_t)Bb * Hh;            // [B, N2]
    float* attno = cto + (size_t)Bb * N2n;           // [B, TK]
    float* pgo   = attno + (size_t)Bb * TKk;         // [B]
    float* covo  = pgo + Bb;                         // [B, TK]

    float* ws  = (float*)d_ws;
    float* pMw = ws;                                 // [128, PSTR]
    float* pSw = pMw + (size_t)Bb * PSTR;            // [128, PSTR]
    unsigned short* abf = (unsigned short*)(pSw + (size_t)Bb * PSTR); // [128,256] bf16

    k_pre<<<Bb, 1024, 0, stream>>>(y, ct1, emb, Wx, bx, h0, c0,
                                   wih, bih, whh, bhh, Wp, bp,
                                   ef, cov, Wc, vw, mask, eo,
                                   W1, b1, Wpg, bpg,
                                   h1o, c1o, cto, attno, covo, pgo, abf);
    k_gemm<<<GNBLK, 256, 0, stream>>>(abf, W2, b2, fd, pMw, pSw);
    k_vs<<<Bb, 1024, 0, stream>>>(pMw, pSw, pgo, xz, ebev, attno, fd);
}